// Round 4
// baseline (433.538 us; speedup 1.0000x reference)
//
#include <hip/hip_runtime.h>
#include <hip/hip_fp16.h>

// out[r] = sum_{e: row[e]==r} val[e] * embs[col[e]]
// N_NODES = 100000, N_EDGES = 3200000, D = 128, fp32.
//
// Pipeline (8 dispatches):
//   memset      : padded cbcnt/gcur + done (~33 KB)
//   k_hist_conv : [hist blocks] coarse 512-row bucket counts (LDS) -> padded
//                 cbcnt; last hist block scans -> cstart and seeds padded gcur
//                 [conv blocks] embs fp32 -> fp16
//   k_part1     : LDS-staged coarse partition (shfl scan, wave-per-run
//                 write-out) -> tmp1 (= d_out alias)   [~15 us, R2-bounded]
//   k_cnt       : per-(bucket,slice) row histogram -> scnt  (replaces part2
//                 phase 1; 4x block parallelism: 196 blocks was 1 block/CU)
//   k_scat2     : per-(bucket,slice) scan of slice hists + scatter -> pcv,
//                 CSR row_start/row_cnt (replaces part2 phases 2-3)
//   k_rows_h x4 : one wave per row, register accumulate, fp16 gathers
//                 (exact R0 body; split into 4 row-range dispatches ~38 us
//                 each so rocprof top-5 can show preprocessing kernels)
//
// HW lessons baked in:
//   - per-edge device-scope global atomics ~14 G/s -> never (R2: +220 us).
//   - fp32 LDS atomics = CAS loop (15x); int LDS atomics only.
//   - NT loads / manual pipelining in rows_h regressed (R1): keep R0 body.
//   - counter padding / scan micro-opts: neutral (R3) — the 247 us of
//     preprocessing is structural, prime suspect is part2's 196-block grid.

#define D_FEAT 128
#define CSHIFT 9             // 512 rows per coarse bucket
#define CROWS 512
#define MAXNBC 256
#define PAD 16               // ints per padded counter (64 B)
#define EPT 16
#define BLK 256
#define EPB (BLK * EPT)      // 4096 edges per partition block
#define NS 4                 // slices per coarse bucket (k_cnt/k_scat2)

// ---- 64-lane inclusive scan via shfl
__device__ __forceinline__ int wave_incl_scan(int x, int lane) {
#pragma unroll
    for (int off = 1; off < 64; off <<= 1) {
        int y = __shfl_up(x, off, 64);
        if (lane >= off) x += y;
    }
    return x;
}

// ---------- fused: coarse histogram (+last-block scan) and embs fp32->fp16 ----------
__global__ __launch_bounds__(256) void k_hist_conv(const int* __restrict__ row,
                                                   int* __restrict__ cbcnt,   // padded
                                                   int* __restrict__ cstart,
                                                   int* __restrict__ gcur,    // padded
                                                   int* __restrict__ done,
                                                   int n_edges, int nbc, int hist_blocks,
                                                   const float* __restrict__ embs,
                                                   __half* __restrict__ embs16,
                                                   int n_f4pairs) {
    int tid = threadIdx.x;
    if ((int)blockIdx.x >= hist_blocks) {
        // ---- conv part: 2x float4 (8 floats) per thread ----
        int i = (blockIdx.x - hist_blocks) * 256 + tid;
        if (i >= n_f4pairs) return;
        const float4* src = reinterpret_cast<const float4*>(embs) + (size_t)i * 2;
        float4 f0 = src[0];
        float4 f1 = src[1];
        __half2* dst = reinterpret_cast<__half2*>(embs16) + (size_t)i * 4;
        dst[0] = __floats2half2_rn(f0.x, f0.y);
        dst[1] = __floats2half2_rn(f0.z, f0.w);
        dst[2] = __floats2half2_rn(f1.x, f1.y);
        dst[3] = __floats2half2_rn(f1.z, f1.w);
        return;
    }
    // ---- hist part ----
    __shared__ int l[MAXNBC];
    __shared__ int s[256];
    __shared__ int lastflag;
    for (int j = tid; j < nbc; j += 256) l[j] = 0;
    __syncthreads();
    int base = blockIdx.x * EPB;
#pragma unroll
    for (int k = 0; k < EPT; ++k) {
        int e = base + k * 256 + tid;
        if (e < n_edges) atomicAdd(&l[row[e] >> CSHIFT], 1);
    }
    __syncthreads();
    for (int j = tid; j < nbc; j += 256)
        if (l[j]) atomicAdd(&cbcnt[j * PAD], l[j]);   // padded: one line per bucket
    __threadfence();
    if (tid == 0) lastflag = (atomicAdd(done, 1) == hist_blocks - 1);
    __syncthreads();
    if (!lastflag) return;
    // ---- last hist block: exclusive scan of cbcnt -> cstart, seed gcur ----
    int v = (tid < nbc) ? __hip_atomic_load(&cbcnt[tid * PAD], __ATOMIC_RELAXED,
                                            __HIP_MEMORY_SCOPE_AGENT) : 0;
    s[tid] = v;
    __syncthreads();
    for (int off = 1; off < 256; off <<= 1) {
        int u = (tid >= off) ? s[tid - off] : 0;
        __syncthreads();
        s[tid] += u;
        __syncthreads();
    }
    if (tid < nbc) {
        int ex = s[tid] - v;
        cstart[tid] = ex;
        gcur[tid * PAD] = ex;                          // part1 bumps from cstart
        if (tid == nbc - 1) cstart[nbc] = s[tid];
    }
}

// ---------- pass 1: LDS-staged coarse partition, coalesced run writes ----------
__global__ __launch_bounds__(BLK) void k_part1(const int* __restrict__ row,
                                               const int* __restrict__ col,
                                               const float* __restrict__ val,
                                               int* __restrict__ gcur,    // padded
                                               int2* __restrict__ tmp1,
                                               int n_edges, int nbc) {
    __shared__ int2 stage[EPB];                 // 32 KB
    __shared__ int lcnt[MAXNBC], lstart[MAXNBC + 1], lcur[MAXNBC], lbase[MAXNBC];
    __shared__ int wsum[4];
    int tid = threadIdx.x, lane = tid & 63, wid = tid >> 6;
    for (int j = tid; j < nbc; j += BLK) { lcnt[j] = 0; lcur[j] = 0; }
    __syncthreads();

    int base = blockIdx.x * EPB;

    int r[EPT], c[EPT]; float v[EPT];
#pragma unroll
    for (int k = 0; k < EPT; ++k) {
        int e = base + k * BLK + tid;
        r[k] = -1;
        if (e < n_edges) {
            r[k] = row[e]; c[k] = col[e]; v[k] = val[e];
            atomicAdd(&lcnt[r[k] >> CSHIFT], 1);
        }
    }
    __syncthreads();
    // exclusive scan of lcnt (shfl, 2 barriers)
    int cv = (tid < nbc) ? lcnt[tid] : 0;
    int incl = wave_incl_scan(cv, lane);
    if (lane == 63) wsum[wid] = incl;
    __syncthreads();
    if (tid < 4) {
        int w = wsum[tid];
        int ss = w;
#pragma unroll
        for (int off = 1; off < 4; off <<= 1) {
            int y = __shfl_up(ss, off, 64);
            if (tid >= off) ss += y;
        }
        wsum[tid] = ss - w;
    }
    __syncthreads();
    int ex = wsum[wid] + incl - cv;
    if (tid < nbc) {
        lstart[tid] = ex;
        if (cv) lbase[tid] = atomicAdd(&gcur[tid * PAD], cv);  // padded, pre-seeded
    }
    if (tid == BLK - 1) lstart[nbc] = ex + cv;   // block total (cv=0 for tid>=nbc)
    __syncthreads();
    // place into LDS stage, bucket-sorted
#pragma unroll
    for (int k = 0; k < EPT; ++k) {
        if (r[k] >= 0) {
            int b = r[k] >> CSHIFT;
            int slot = lstart[b] + atomicAdd(&lcur[b], 1);
            stage[slot] = make_int2(((r[k] & (CROWS - 1)) << 17) | c[k],
                                    __float_as_int(v[k]));
        }
    }
    __syncthreads();
    // write-out: wave per bucket-run (coalesced LDS reads, contiguous global runs)
    for (int j = wid; j < nbc; j += (BLK / 64)) {
        int n = lcnt[j];
        if (!n) continue;
        int ls = lstart[j], lb = lbase[j];
        for (int t = lane; t < n; t += 64)
            tmp1[lb + t] = stage[ls + t];
    }
}

// ---------- k_cnt: per-(bucket,slice) row histogram -> scnt[b][s][CROWS] ----------
__global__ __launch_bounds__(256) void k_cnt(const int2* __restrict__ tmp1,
                                             const int* __restrict__ cstart,
                                             int* __restrict__ scnt) {
    __shared__ int rc[CROWS];
    int b = blockIdx.x / NS, s = blockIdx.x % NS, tid = threadIdx.x;
    int base = cstart[b], end = cstart[b + 1];
    int len = end - base;
    int chunk = (len + NS - 1) / NS;
    int lo = base + s * chunk;
    int hi = lo + chunk; if (hi > end) hi = end;
    for (int j = tid; j < CROWS; j += 256) rc[j] = 0;
    __syncthreads();
    for (int i = lo + tid; i < hi; i += 256)
        atomicAdd(&rc[((unsigned)tmp1[i].x) >> 17], 1);
    __syncthreads();
    int* dst = scnt + ((size_t)b * NS + s) * CROWS;
    for (int j = tid; j < CROWS; j += 256) dst[j] = rc[j];
}

// ---------- k_scat2: per-(bucket,slice) scan + scatter -> pcv, CSR ----------
__global__ __launch_bounds__(256) void k_scat2(const int2* __restrict__ tmp1,
                                               const int* __restrict__ cstart,
                                               const int* __restrict__ scnt,
                                               int2* __restrict__ pcv,
                                               int* __restrict__ row_start,
                                               int* __restrict__ row_cnt,
                                               int n_nodes) {
    __shared__ int rstart[CROWS], soff[CROWS], rtot[CROWS], rcur[CROWS];
    __shared__ int wsum[4];
    int b = blockIdx.x / NS, s = blockIdx.x % NS, tid = threadIdx.x;
    int lane = tid & 63, wid = tid >> 6;
    int base = cstart[b], end = cstart[b + 1];
    int len = end - base;
    int chunk = (len + NS - 1) / NS;
    int lo = base + s * chunk;
    int hi = lo + chunk; if (hi > end) hi = end;

    // load 4 slice histograms for this bucket; per-thread rows 2t, 2t+1
    const int* sc = scnt + (size_t)b * NS * CROWS;
    int r0 = 2 * tid, r1 = 2 * tid + 1;
    int t0 = 0, t1 = 0, o0 = 0, o1 = 0;
#pragma unroll
    for (int ss = 0; ss < NS; ++ss) {
        int c0 = sc[ss * CROWS + r0];
        int c1 = sc[ss * CROWS + r1];
        t0 += c0; t1 += c1;
        if (ss < s) { o0 += c0; o1 += c1; }
    }
    rtot[r0] = t0; rtot[r1] = t1;
    soff[r0] = o0; soff[r1] = o1;
    rcur[r0] = 0;  rcur[r1] = 0;
    // pair-sum scan over 512 via 256-thread shfl scan
    int pv = t0 + t1;
    int incl = wave_incl_scan(pv, lane);
    if (lane == 63) wsum[wid] = incl;
    __syncthreads();
    if (tid < 4) {
        int w = wsum[tid];
        int sx = w;
#pragma unroll
        for (int off = 1; off < 4; off <<= 1) {
            int y = __shfl_up(sx, off, 64);
            if (tid >= off) sx += y;
        }
        wsum[tid] = sx - w;
    }
    __syncthreads();
    int ex = wsum[wid] + incl - pv;
    rstart[r0] = ex;
    rstart[r1] = ex + t0;
    __syncthreads();
    // CSR metadata (slice 0 only)
    if (s == 0) {
        for (int j = tid; j < CROWS; j += 256) {
            int gr = (b << CSHIFT) + j;
            if (gr < n_nodes) {
                row_start[gr] = base + rstart[j];
                row_cnt[gr]   = rtot[j];
            }
        }
    }
    // scatter own slice; positions disjoint across slices (no cross-slice atomics)
    for (int i = lo + tid; i < hi; i += 256) {
        int2 p = tmp1[i];
        int lr = ((unsigned)p.x) >> 17;
        int pos = base + rstart[lr] + soff[lr] + atomicAdd(&rcur[lr], 1);
        pcv[pos] = make_int2(p.x & 0x1FFFF, p.y);
    }
}

// ---------- accumulate: one wave per row, fp16 gathers (exact R0 body, row-range) ----------
__global__ __launch_bounds__(256) void k_rows_h(const int2* __restrict__ pcv,
                                                const int* __restrict__ row_start,
                                                const int* __restrict__ row_cnt,
                                                const __half2* __restrict__ eb,
                                                float* __restrict__ out,
                                                int r_begin, int r_end) {
    int gtid = blockIdx.x * blockDim.x + threadIdx.x;
    int r = r_begin + (gtid >> 6);
    int lane = threadIdx.x & 63;
    if (r >= r_end) return;

    int start = row_start[r];
    int end   = start + row_cnt[r];

    float2 acc = make_float2(0.f, 0.f);

    int i = start;
    for (; i + 8 <= end; i += 8) {
        int2 p[8];
#pragma unroll
        for (int k = 0; k < 8; ++k) p[k] = pcv[i + k];
        __half2 h[8];
#pragma unroll
        for (int k = 0; k < 8; ++k) h[k] = eb[(size_t)p[k].x * 64 + lane];
#pragma unroll
        for (int k = 0; k < 8; ++k) {
            float v = __int_as_float(p[k].y);
            float2 f = __half22float2(h[k]);
            acc.x += v * f.x;
            acc.y += v * f.y;
        }
    }
    for (; i < end; ++i) {
        int2 p = pcv[i];
        float v = __int_as_float(p.y);
        float2 f = __half22float2(eb[(size_t)p.x * 64 + lane]);
        acc.x += v * f.x;
        acc.y += v * f.y;
    }
    reinterpret_cast<float2*>(out)[(size_t)r * 64 + lane] = acc;
}

// ---------- fallback: atomic scatter ----------
__global__ void gcn_scatter_atomic(const int* __restrict__ edge_row,
                                   const int* __restrict__ edge_col,
                                   const float* __restrict__ edge_val,
                                   const float* __restrict__ embs,
                                   float* __restrict__ out, int n_edges) {
    long long tid = (long long)blockIdx.x * blockDim.x + threadIdx.x;
    int sub = (int)(tid & 31);
    long long edge = tid >> 5;
    if (edge >= n_edges) return;
    int r = edge_row[edge];
    int c = edge_col[edge];
    float v = edge_val[edge];
    const float4* src = reinterpret_cast<const float4*>(embs + (size_t)c * D_FEAT);
    float4 m = src[sub];
    float* dst = out + (size_t)r * D_FEAT + (size_t)sub * 4;
    atomicAdd(dst + 0, m.x * v);
    atomicAdd(dst + 1, m.y * v);
    atomicAdd(dst + 2, m.z * v);
    atomicAdd(dst + 3, m.w * v);
}

extern "C" void kernel_launch(void* const* d_in, const int* in_sizes, int n_in,
                              void* d_out, int out_size, void* d_ws, size_t ws_size,
                              hipStream_t stream) {
    const int*   edge_row = (const int*)d_in[0];
    const int*   edge_col = (const int*)d_in[1];
    const float* edge_val = (const float*)d_in[2];
    const float* embs     = (const float*)d_in[3];
    float*       out      = (float*)d_out;

    const int n_edges = in_sizes[0];
    const int n_nodes = out_size / D_FEAT;
    const int nbc = (n_nodes + CROWS - 1) >> CSHIFT;

    // Workspace layout
    char* ws = (char*)d_ws;
    const size_t off_pcv       = 0;
    const size_t off_row_start = off_pcv + (size_t)n_edges * 8;
    const size_t off_row_cnt   = off_row_start + (size_t)n_nodes * 4;
    const size_t off_cbcnt     = off_row_cnt + (size_t)n_nodes * 4;   // padded, memset base
    const size_t off_gcur      = off_cbcnt + (size_t)MAXNBC * PAD * 4;
    const size_t off_done      = off_gcur + (size_t)MAXNBC * PAD * 4;
    const size_t memset_len    = (size_t)MAXNBC * PAD * 8 + 16;
    const size_t off_cstart    = off_done + 16;
    const size_t off_scnt      = (off_cstart + (size_t)(MAXNBC + 1) * 4 + 15) & ~(size_t)15;
    const size_t off_embs16    = off_scnt + (size_t)nbc * NS * CROWS * 4;
    const size_t full_ws       = off_embs16 + (size_t)n_nodes * D_FEAT * 2;

    // tmp1 aliases d_out (consumed by k_cnt/k_scat2 before k_rows_h writes out).
    bool tmp_fits = ((size_t)n_edges * 8 <= (size_t)out_size * 4);
    bool packs_ok = (n_nodes <= 131072) && (nbc <= MAXNBC);  // 17-bit col, 9-bit lr

    if (ws_size < full_ws || !tmp_fits || !packs_ok) {
        hipMemsetAsync(d_out, 0, (size_t)out_size * sizeof(float), stream);
        long long total = (long long)n_edges * 32;
        int blocks = (int)((total + 255) / 256);
        gcn_scatter_atomic<<<blocks, 256, 0, stream>>>(edge_row, edge_col, edge_val,
                                                       embs, out, n_edges);
        return;
    }

    int2*   pcv       = (int2*)(ws + off_pcv);
    int*    row_start = (int*)(ws + off_row_start);
    int*    row_cnt   = (int*)(ws + off_row_cnt);
    int*    cbcnt     = (int*)(ws + off_cbcnt);
    int*    gcur      = (int*)(ws + off_gcur);
    int*    done      = (int*)(ws + off_done);
    int*    cstart    = (int*)(ws + off_cstart);
    int*    scnt      = (int*)(ws + off_scnt);
    __half* embs16    = (__half*)(ws + off_embs16);
    int2*   tmp1      = (int2*)d_out;

    // zero padded cbcnt + gcur + done in one shot (~33 KB)
    hipMemsetAsync(cbcnt, 0, memset_len, stream);

    const int nchunks = (n_edges + EPB - 1) / EPB;
    const int nf4p = n_nodes * (D_FEAT / 8);       // 2x float4 per thread
    const int conv_blocks = (nf4p + 255) / 256;

    k_hist_conv<<<nchunks + conv_blocks, 256, 0, stream>>>(
        edge_row, cbcnt, cstart, gcur, done, n_edges, nbc, nchunks,
        embs, embs16, nf4p);
    k_part1<<<nchunks, BLK, 0, stream>>>(edge_row, edge_col, edge_val,
                                         gcur, tmp1, n_edges, nbc);
    k_cnt<<<nbc * NS, 256, 0, stream>>>(tmp1, cstart, scnt);
    k_scat2<<<nbc * NS, 256, 0, stream>>>(tmp1, cstart, scnt, pcv,
                                          row_start, row_cnt, n_nodes);

    // rows_h split into 4 row-range dispatches (~38 us each) so rocprof top-5
    // can expose preprocessing kernels (>38 us shows up).
    int q = (n_nodes + 3) / 4;
    for (int k = 0; k < 4; ++k) {
        int r0 = k * q;
        int r1 = r0 + q; if (r1 > n_nodes) r1 = n_nodes;
        if (r1 <= r0) continue;
        long long thr = (long long)(r1 - r0) * 64;
        int blocks = (int)((thr + 255) / 256);
        k_rows_h<<<blocks, 256, 0, stream>>>(pcv, row_start, row_cnt,
                                             (const __half2*)embs16, out, r0, r1);
    }
}

// Round 6
// 388.789 us; speedup vs baseline: 1.1151x; 1.1151x over previous
//
#include <hip/hip_runtime.h>
#include <hip/hip_fp16.h>

// out[r] = sum_{e: row[e]==r} val[e] * embs[col[e]]
// N_NODES = 100000, N_EDGES = 3200000, D = 128, fp32.
//
// Pipeline (8 dispatches, no memset):
//   k_hist_conv : [256 grid-stride hist blocks] private per-block coarse
//                 histogram rows (plain stores — NO global atomics, NO fence;
//                 R4 showed 782-deep same-line atomics + threadfence = 78 us)
//                 [conv blocks] embs fp32 -> fp16
//   k_cscan     : 1 block: column-sum the 256 hist rows, scan -> cstart,
//                 seed padded gcur
//   k_part1     : LDS-staged coarse partition (shfl scan, wave-per-run
//                 write-out) -> tmp1 (= d_out alias)
//   k_part2     : per-bucket counting sort @1024 thr (R3 version — R4's
//                 sliced cnt+scat2 was 35 us WORSE; revert)
//   k_rows_h x4 : one wave per row, register accumulate, fp16 gathers
//                 (exact R0 body; 4 row-range dispatches keep rocprof top-5
//                 able to expose any preprocessing kernel >38 us)
//
// HW lessons:
//   - per-edge device-scope atomics ~14 G/s (R2: +220 us) -> never.
//   - contended same-line device atomics + threadfence stall waves for the
//     full coherence-point queue (R4: hist_conv 78 us, VALUBusy 1.2%).
//   - fp32 LDS atomics = CAS loop (15x); int LDS atomics only.
//   - NT loads / manual pipelining in rows_h regressed (R1): keep R0 body.
//   - slicing the scatter for parallelism regressed (R4): keep integrated
//     per-bucket part2.

#define D_FEAT 128
#define CSHIFT 9             // 512 rows per coarse bucket
#define CROWS 512
#define MAXNBC 256
#define PAD 16               // ints per padded counter (64 B)
#define EPT 16
#define BLK 256
#define EPB (BLK * EPT)      // 4096 edges per partition block
#define BLK2 1024            // k_part2 block size
#define HB 256               // hist blocks (grid-stride)

// ---- 64-lane inclusive scan via shfl
__device__ __forceinline__ int wave_incl_scan(int x, int lane) {
#pragma unroll
    for (int off = 1; off < 64; off <<= 1) {
        int y = __shfl_up(x, off, 64);
        if (lane >= off) x += y;
    }
    return x;
}

// ---------- fused: private-row coarse histogram and embs fp32->fp16 ----------
__global__ __launch_bounds__(256) void k_hist_conv(const int* __restrict__ row,
                                                   int* __restrict__ cbhist,  // [HB][MAXNBC]
                                                   int n_edges, int nbc,
                                                   const float* __restrict__ embs,
                                                   __half* __restrict__ embs16,
                                                   int n_f4pairs) {
    int tid = threadIdx.x;
    if ((int)blockIdx.x >= HB) {
        // ---- conv part: 2x float4 (8 floats) per thread ----
        int i = (blockIdx.x - HB) * 256 + tid;
        if (i >= n_f4pairs) return;
        const float4* src = reinterpret_cast<const float4*>(embs) + (size_t)i * 2;
        float4 f0 = src[0];
        float4 f1 = src[1];
        __half2* dst = reinterpret_cast<__half2*>(embs16) + (size_t)i * 4;
        dst[0] = __floats2half2_rn(f0.x, f0.y);
        dst[1] = __floats2half2_rn(f0.z, f0.w);
        dst[2] = __floats2half2_rn(f1.x, f1.y);
        dst[3] = __floats2half2_rn(f1.z, f1.w);
        return;
    }
    // ---- hist part: grid-stride, private output row, zero global atomics ----
    __shared__ int l[MAXNBC];
    for (int j = tid; j < nbc; j += 256) l[j] = 0;
    __syncthreads();
    const int stride = HB * 256;
    for (int e = blockIdx.x * 256 + tid; e < n_edges; e += stride)
        atomicAdd(&l[row[e] >> CSHIFT], 1);
    __syncthreads();
    int* dst = cbhist + (size_t)blockIdx.x * MAXNBC;
    for (int j = tid; j < nbc; j += 256) dst[j] = l[j];
}

// ---------- 1-block: reduce hist rows, exclusive scan -> cstart, seed gcur ----------
__global__ __launch_bounds__(256) void k_cscan(const int* __restrict__ cbhist,
                                               int* __restrict__ cstart,
                                               int* __restrict__ gcur,   // padded
                                               int nbc) {
    __shared__ int s[256];
    int t = threadIdx.x;
    int v = 0;
    if (t < nbc)
        for (int b = 0; b < HB; ++b)
            v += cbhist[(size_t)b * MAXNBC + t];   // coalesced across threads
    s[t] = v;
    __syncthreads();
    for (int off = 1; off < 256; off <<= 1) {
        int u = (t >= off) ? s[t - off] : 0;
        __syncthreads();
        s[t] += u;
        __syncthreads();
    }
    if (t < nbc) {
        int ex = s[t] - v;
        cstart[t] = ex;
        gcur[t * PAD] = ex;                        // part1 bumps from cstart
        if (t == nbc - 1) cstart[nbc] = s[t];
    }
}

// ---------- pass 1: LDS-staged coarse partition, coalesced run writes ----------
__global__ __launch_bounds__(BLK) void k_part1(const int* __restrict__ row,
                                               const int* __restrict__ col,
                                               const float* __restrict__ val,
                                               int* __restrict__ gcur,    // padded
                                               int2* __restrict__ tmp1,
                                               int n_edges, int nbc) {
    __shared__ int2 stage[EPB];                 // 32 KB
    __shared__ int lcnt[MAXNBC], lstart[MAXNBC + 1], lcur[MAXNBC], lbase[MAXNBC];
    __shared__ int wsum[4];
    int tid = threadIdx.x, lane = tid & 63, wid = tid >> 6;
    for (int j = tid; j < nbc; j += BLK) { lcnt[j] = 0; lcur[j] = 0; }
    __syncthreads();

    int base = blockIdx.x * EPB;

    int r[EPT], c[EPT]; float v[EPT];
#pragma unroll
    for (int k = 0; k < EPT; ++k) {
        int e = base + k * BLK + tid;
        r[k] = -1;
        if (e < n_edges) {
            r[k] = row[e]; c[k] = col[e]; v[k] = val[e];
            atomicAdd(&lcnt[r[k] >> CSHIFT], 1);
        }
    }
    __syncthreads();
    // exclusive scan of lcnt (shfl, 2 barriers)
    int cv = (tid < nbc) ? lcnt[tid] : 0;
    int incl = wave_incl_scan(cv, lane);
    if (lane == 63) wsum[wid] = incl;
    __syncthreads();
    if (tid < 4) {
        int w = wsum[tid];
        int ss = w;
#pragma unroll
        for (int off = 1; off < 4; off <<= 1) {
            int y = __shfl_up(ss, off, 64);
            if (tid >= off) ss += y;
        }
        wsum[tid] = ss - w;
    }
    __syncthreads();
    int ex = wsum[wid] + incl - cv;
    if (tid < nbc) {
        lstart[tid] = ex;
        if (cv) lbase[tid] = atomicAdd(&gcur[tid * PAD], cv);  // padded, pre-seeded
    }
    if (tid == BLK - 1) lstart[nbc] = ex + cv;   // block total (cv=0 for tid>=nbc)
    __syncthreads();
    // place into LDS stage, bucket-sorted
#pragma unroll
    for (int k = 0; k < EPT; ++k) {
        if (r[k] >= 0) {
            int b = r[k] >> CSHIFT;
            int slot = lstart[b] + atomicAdd(&lcur[b], 1);
            stage[slot] = make_int2(((r[k] & (CROWS - 1)) << 17) | c[k],
                                    __float_as_int(v[k]));
        }
    }
    __syncthreads();
    // write-out: wave per bucket-run (coalesced LDS reads, contiguous global runs)
    for (int j = wid; j < nbc; j += (BLK / 64)) {
        int n = lcnt[j];
        if (!n) continue;
        int ls = lstart[j], lb = lbase[j];
        for (int t = lane; t < n; t += 64)
            tmp1[lb + t] = stage[ls + t];
    }
}

// ---------- pass 2: per-coarse-bucket counting sort -> pcv + CSR ----------
__global__ __launch_bounds__(BLK2) void k_part2(const int2* __restrict__ tmp1,
                                                const int* __restrict__ cstart,
                                                int2* __restrict__ pcv,
                                                int* __restrict__ row_start,
                                                int* __restrict__ row_cnt,
                                                int n_nodes) {
    __shared__ int rcnt[CROWS], rstart[CROWS], rcur[CROWS];
    __shared__ int wsum[8];
    int b = blockIdx.x, tid = threadIdx.x;
    int lane = tid & 63, wid = tid >> 6;
    int base = cstart[b], end = cstart[b + 1];

    for (int j = tid; j < CROWS; j += BLK2) { rcnt[j] = 0; rcur[j] = 0; }
    __syncthreads();
    for (int i = base + tid; i < end; i += BLK2) {
        int lr = ((unsigned)tmp1[i].x) >> 17;
        atomicAdd(&rcnt[lr], 1);
    }
    __syncthreads();
    // exclusive scan over 512 counts (waves 0-7, shfl; 3 barriers total)
    int v = (tid < CROWS) ? rcnt[tid] : 0;
    int incl = wave_incl_scan(v, lane);
    if (lane == 63 && wid < 8) wsum[wid] = incl;
    __syncthreads();
    if (tid < 8) {
        int w = wsum[tid];
        int ss = w;
#pragma unroll
        for (int off = 1; off < 8; off <<= 1) {
            int y = __shfl_up(ss, off, 64);
            if (tid >= off) ss += y;
        }
        wsum[tid] = ss - w;
    }
    __syncthreads();
    if (tid < CROWS) rstart[tid] = wsum[wid] + incl - v;
    __syncthreads();
    // emit CSR metadata
    if (tid < CROWS) {
        int gr = (b << CSHIFT) + tid;
        if (gr < n_nodes) {
            row_start[gr] = base + rstart[tid];
            row_cnt[gr]   = v;
        }
    }
    // scatter to row-sorted positions (block-private ~130 KB window, L2-hot)
    for (int i = base + tid; i < end; i += BLK2) {
        int2 p = tmp1[i];
        int lr = ((unsigned)p.x) >> 17;
        int pos = base + rstart[lr] + atomicAdd(&rcur[lr], 1);
        pcv[pos] = make_int2(p.x & 0x1FFFF, p.y);
    }
}

// ---------- accumulate: one wave per row, fp16 gathers (exact R0 body, row-range) ----------
__global__ __launch_bounds__(256) void k_rows_h(const int2* __restrict__ pcv,
                                                const int* __restrict__ row_start,
                                                const int* __restrict__ row_cnt,
                                                const __half2* __restrict__ eb,
                                                float* __restrict__ out,
                                                int r_begin, int r_end) {
    int gtid = blockIdx.x * blockDim.x + threadIdx.x;
    int r = r_begin + (gtid >> 6);
    int lane = threadIdx.x & 63;
    if (r >= r_end) return;

    int start = row_start[r];
    int end   = start + row_cnt[r];

    float2 acc = make_float2(0.f, 0.f);

    int i = start;
    for (; i + 8 <= end; i += 8) {
        int2 p[8];
#pragma unroll
        for (int k = 0; k < 8; ++k) p[k] = pcv[i + k];
        __half2 h[8];
#pragma unroll
        for (int k = 0; k < 8; ++k) h[k] = eb[(size_t)p[k].x * 64 + lane];
#pragma unroll
        for (int k = 0; k < 8; ++k) {
            float v = __int_as_float(p[k].y);
            float2 f = __half22float2(h[k]);
            acc.x += v * f.x;
            acc.y += v * f.y;
        }
    }
    for (; i < end; ++i) {
        int2 p = pcv[i];
        float v = __int_as_float(p.y);
        float2 f = __half22float2(eb[(size_t)p.x * 64 + lane]);
        acc.x += v * f.x;
        acc.y += v * f.y;
    }
    reinterpret_cast<float2*>(out)[(size_t)r * 64 + lane] = acc;
}

// ---------- fallback: atomic scatter ----------
__global__ void gcn_scatter_atomic(const int* __restrict__ edge_row,
                                   const int* __restrict__ edge_col,
                                   const float* __restrict__ edge_val,
                                   const float* __restrict__ embs,
                                   float* __restrict__ out, int n_edges) {
    long long tid = (long long)blockIdx.x * blockDim.x + threadIdx.x;
    int sub = (int)(tid & 31);
    long long edge = tid >> 5;
    if (edge >= n_edges) return;
    int r = edge_row[edge];
    int c = edge_col[edge];
    float v = edge_val[edge];
    const float4* src = reinterpret_cast<const float4*>(embs + (size_t)c * D_FEAT);
    float4 m = src[sub];
    float* dst = out + (size_t)r * D_FEAT + (size_t)sub * 4;
    atomicAdd(dst + 0, m.x * v);
    atomicAdd(dst + 1, m.y * v);
    atomicAdd(dst + 2, m.z * v);
    atomicAdd(dst + 3, m.w * v);
}

extern "C" void kernel_launch(void* const* d_in, const int* in_sizes, int n_in,
                              void* d_out, int out_size, void* d_ws, size_t ws_size,
                              hipStream_t stream) {
    const int*   edge_row = (const int*)d_in[0];
    const int*   edge_col = (const int*)d_in[1];
    const float* edge_val = (const float*)d_in[2];
    const float* embs     = (const float*)d_in[3];
    float*       out      = (float*)d_out;

    const int n_edges = in_sizes[0];
    const int n_nodes = out_size / D_FEAT;
    const int nbc = (n_nodes + CROWS - 1) >> CSHIFT;

    // Workspace layout
    char* ws = (char*)d_ws;
    const size_t off_pcv       = 0;
    const size_t off_row_start = off_pcv + (size_t)n_edges * 8;
    const size_t off_row_cnt   = off_row_start + (size_t)n_nodes * 4;
    const size_t off_cbhist    = off_row_cnt + (size_t)n_nodes * 4;
    const size_t off_gcur      = off_cbhist + (size_t)HB * MAXNBC * 4;
    const size_t off_cstart    = off_gcur + (size_t)MAXNBC * PAD * 4;
    const size_t off_embs16    = (off_cstart + (size_t)(MAXNBC + 1) * 4 + 15) & ~(size_t)15;
    const size_t full_ws       = off_embs16 + (size_t)n_nodes * D_FEAT * 2;

    // tmp1 aliases d_out (consumed by k_part2 before k_rows_h writes out).
    bool tmp_fits = ((size_t)n_edges * 8 <= (size_t)out_size * 4);
    bool packs_ok = (n_nodes <= 131072) && (nbc <= MAXNBC);  // 17-bit col, 9-bit lr

    if (ws_size < full_ws || !tmp_fits || !packs_ok) {
        hipMemsetAsync(d_out, 0, (size_t)out_size * sizeof(float), stream);
        long long total = (long long)n_edges * 32;
        int blocks = (int)((total + 255) / 256);
        gcn_scatter_atomic<<<blocks, 256, 0, stream>>>(edge_row, edge_col, edge_val,
                                                       embs, out, n_edges);
        return;
    }

    int2*   pcv       = (int2*)(ws + off_pcv);
    int*    row_start = (int*)(ws + off_row_start);
    int*    row_cnt   = (int*)(ws + off_row_cnt);
    int*    cbhist    = (int*)(ws + off_cbhist);
    int*    gcur      = (int*)(ws + off_gcur);
    int*    cstart    = (int*)(ws + off_cstart);
    __half* embs16    = (__half*)(ws + off_embs16);
    int2*   tmp1      = (int2*)d_out;

    const int nchunks = (n_edges + EPB - 1) / EPB;
    const int nf4p = n_nodes * (D_FEAT / 8);       // 2x float4 per thread
    const int conv_blocks = (nf4p + 255) / 256;

    k_hist_conv<<<HB + conv_blocks, 256, 0, stream>>>(
        edge_row, cbhist, n_edges, nbc, embs, embs16, nf4p);
    k_cscan<<<1, 256, 0, stream>>>(cbhist, cstart, gcur, nbc);
    k_part1<<<nchunks, BLK, 0, stream>>>(edge_row, edge_col, edge_val,
                                         gcur, tmp1, n_edges, nbc);
    k_part2<<<nbc, BLK2, 0, stream>>>(tmp1, cstart, pcv, row_start, row_cnt, n_nodes);

    // rows_h split into 4 row-range dispatches (~38 us each): keeps rocprof
    // top-5 able to surface any preprocessing kernel that exceeds ~38 us.
    int q = (n_nodes + 3) / 4;
    for (int k = 0; k < 4; ++k) {
        int r0 = k * q;
        int r1 = r0 + q; if (r1 > n_nodes) r1 = n_nodes;
        if (r1 <= r0) continue;
        long long thr = (long long)(r1 - r0) * 64;
        int blocks = (int)((thr + 255) / 256);
        k_rows_h<<<blocks, 256, 0, stream>>>(pcv, row_start, row_cnt,
                                             (const __half2*)embs16, out, r0, r1);
    }
}

// Round 7
// 380.923 us; speedup vs baseline: 1.1381x; 1.0206x over previous
//
#include <hip/hip_runtime.h>
#include <hip/hip_fp16.h>

// out[r] = sum_{e: row[e]==r} val[e] * embs[col[e]]
// N_NODES = 100000, N_EDGES = 3200000, D = 128, fp32.
//
// Pipeline (5 dispatches):
//   k_hist_conv : [256 grid-stride hist blocks] private per-block coarse
//                 histogram rows (plain stores — NO global atomics/fence)
//                 [conv blocks] embs fp32 -> fp16
//   k_cscan     : 1 block: column-sum 256 hist rows, scan -> cstart, seed gcur
//   k_part1     : LDS-staged coarse partition -> tmp1 (= d_out alias)
//                 R7: EPT=8 (16KB stage, ~20KB LDS -> 7 blk/CU; grid 1563
//                 ~6/CU) fixes R6's 24% occupancy; write-out = per-element
//                 binary search (wave-per-run wastes 84% lanes at run~10)
//   k_part2     : per-bucket counting sort @1024 thr -> pcv + CSR
//   k_rows_h    : ONE dispatch (R6 4-way split cost 23 us: 174.8 vs 152.2)
//
// HW lessons:
//   - per-edge device-scope atomics ~14 G/s (R2: +220 us) -> never.
//   - contended same-line atomics + threadfence stall the queue (R4: 78 us).
//   - fp32 LDS atomics = CAS loop (15x); int LDS atomics only.
//   - NT loads / manual pipelining in rows_h regressed (R1): keep R0 body.
//   - short edge-pass kernels are ramp/latency-bound, not BW-bound (R6:
//     part1 44 us @ 24% occ, 15% HBM) -> occupancy and dispatch count rule.

#define D_FEAT 128
#define CSHIFT 9             // 512 rows per coarse bucket
#define CROWS 512
#define MAXNBC 256
#define PAD 16               // ints per padded counter (64 B)
#define EPT 8
#define BLK 256
#define EPB (BLK * EPT)      // 2048 edges per partition block
#define BLK2 1024            // k_part2 block size
#define HB 256               // hist blocks (grid-stride)

// ---- 64-lane inclusive scan via shfl
__device__ __forceinline__ int wave_incl_scan(int x, int lane) {
#pragma unroll
    for (int off = 1; off < 64; off <<= 1) {
        int y = __shfl_up(x, off, 64);
        if (lane >= off) x += y;
    }
    return x;
}

// ---------- fused: private-row coarse histogram and embs fp32->fp16 ----------
__global__ __launch_bounds__(256) void k_hist_conv(const int* __restrict__ row,
                                                   int* __restrict__ cbhist,  // [HB][MAXNBC]
                                                   int n_edges, int nbc,
                                                   const float* __restrict__ embs,
                                                   __half* __restrict__ embs16,
                                                   int n_f4pairs) {
    int tid = threadIdx.x;
    if ((int)blockIdx.x >= HB) {
        // ---- conv part: 2x float4 (8 floats) per thread ----
        int i = (blockIdx.x - HB) * 256 + tid;
        if (i >= n_f4pairs) return;
        const float4* src = reinterpret_cast<const float4*>(embs) + (size_t)i * 2;
        float4 f0 = src[0];
        float4 f1 = src[1];
        __half2* dst = reinterpret_cast<__half2*>(embs16) + (size_t)i * 4;
        dst[0] = __floats2half2_rn(f0.x, f0.y);
        dst[1] = __floats2half2_rn(f0.z, f0.w);
        dst[2] = __floats2half2_rn(f1.x, f1.y);
        dst[3] = __floats2half2_rn(f1.z, f1.w);
        return;
    }
    // ---- hist part: grid-stride, private output row, zero global atomics ----
    __shared__ int l[MAXNBC];
    for (int j = tid; j < nbc; j += 256) l[j] = 0;
    __syncthreads();
    const int stride = HB * 256;
    for (int e = blockIdx.x * 256 + tid; e < n_edges; e += stride)
        atomicAdd(&l[row[e] >> CSHIFT], 1);
    __syncthreads();
    int* dst = cbhist + (size_t)blockIdx.x * MAXNBC;
    for (int j = tid; j < nbc; j += 256) dst[j] = l[j];
}

// ---------- 1-block: reduce hist rows, exclusive scan -> cstart, seed gcur ----------
__global__ __launch_bounds__(256) void k_cscan(const int* __restrict__ cbhist,
                                               int* __restrict__ cstart,
                                               int* __restrict__ gcur,   // padded
                                               int nbc) {
    __shared__ int s[256];
    int t = threadIdx.x;
    int v = 0;
    if (t < nbc)
        for (int b = 0; b < HB; ++b)
            v += cbhist[(size_t)b * MAXNBC + t];   // coalesced across threads
    s[t] = v;
    __syncthreads();
    for (int off = 1; off < 256; off <<= 1) {
        int u = (t >= off) ? s[t - off] : 0;
        __syncthreads();
        s[t] += u;
        __syncthreads();
    }
    if (t < nbc) {
        int ex = s[t] - v;
        cstart[t] = ex;
        gcur[t * PAD] = ex;                        // part1 bumps from cstart
        if (t == nbc - 1) cstart[nbc] = s[t];
    }
}

// ---------- pass 1: LDS-staged coarse partition, coalesced run writes ----------
__global__ __launch_bounds__(BLK) void k_part1(const int* __restrict__ row,
                                               const int* __restrict__ col,
                                               const float* __restrict__ val,
                                               int* __restrict__ gcur,    // padded
                                               int2* __restrict__ tmp1,
                                               int n_edges, int nbc) {
    __shared__ int2 stage[EPB];                 // 16 KB
    __shared__ int lcnt[MAXNBC], lstart[MAXNBC + 1], lcur[MAXNBC], lbase[MAXNBC];
    __shared__ int wsum[4];
    int tid = threadIdx.x, lane = tid & 63, wid = tid >> 6;
    for (int j = tid; j < nbc; j += BLK) { lcnt[j] = 0; lcur[j] = 0; }
    __syncthreads();

    int base = blockIdx.x * EPB;
    int ne = n_edges - base; if (ne > EPB) ne = EPB;

    int r[EPT], c[EPT]; float v[EPT];
#pragma unroll
    for (int k = 0; k < EPT; ++k) {
        int e = base + k * BLK + tid;
        r[k] = -1;
        if (e < n_edges) {
            r[k] = row[e]; c[k] = col[e]; v[k] = val[e];
            atomicAdd(&lcnt[r[k] >> CSHIFT], 1);
        }
    }
    __syncthreads();
    // exclusive scan of lcnt (shfl, 2 barriers)
    int cv = (tid < nbc) ? lcnt[tid] : 0;
    int incl = wave_incl_scan(cv, lane);
    if (lane == 63) wsum[wid] = incl;
    __syncthreads();
    if (tid < 4) {
        int w = wsum[tid];
        int ss = w;
#pragma unroll
        for (int off = 1; off < 4; off <<= 1) {
            int y = __shfl_up(ss, off, 64);
            if (tid >= off) ss += y;
        }
        wsum[tid] = ss - w;
    }
    __syncthreads();
    int ex = wsum[wid] + incl - cv;
    if (tid < nbc) {
        lstart[tid] = ex;
        if (cv) lbase[tid] = atomicAdd(&gcur[tid * PAD], cv);  // padded, pre-seeded
    }
    if (tid == BLK - 1) lstart[nbc] = ex + cv;   // block total (cv=0 for tid>=nbc)
    __syncthreads();
    // place into LDS stage, bucket-sorted
#pragma unroll
    for (int k = 0; k < EPT; ++k) {
        if (r[k] >= 0) {
            int b = r[k] >> CSHIFT;
            int slot = lstart[b] + atomicAdd(&lcur[b], 1);
            stage[slot] = make_int2(((r[k] & (CROWS - 1)) << 17) | c[k],
                                    __float_as_int(v[k]));
        }
    }
    __syncthreads();
    // write-out: per-element binary search (R0-proven); consecutive threads
    // hit consecutive slots -> coalesced stores, no idle-lane waste
    for (int i = tid; i < ne; i += BLK) {
        int lo = 0, hi = nbc;
        while (hi - lo > 1) {                    // upper_bound(lstart, i) - 1
            int mid = (lo + hi) >> 1;
            if (lstart[mid] <= i) lo = mid; else hi = mid;
        }
        tmp1[lbase[lo] + (i - lstart[lo])] = stage[i];
    }
}

// ---------- pass 2: per-coarse-bucket counting sort -> pcv + CSR ----------
__global__ __launch_bounds__(BLK2) void k_part2(const int2* __restrict__ tmp1,
                                                const int* __restrict__ cstart,
                                                int2* __restrict__ pcv,
                                                int* __restrict__ row_start,
                                                int* __restrict__ row_cnt,
                                                int n_nodes) {
    __shared__ int rcnt[CROWS], rstart[CROWS], rcur[CROWS];
    __shared__ int wsum[8];
    int b = blockIdx.x, tid = threadIdx.x;
    int lane = tid & 63, wid = tid >> 6;
    int base = cstart[b], end = cstart[b + 1];

    for (int j = tid; j < CROWS; j += BLK2) { rcnt[j] = 0; rcur[j] = 0; }
    __syncthreads();
    for (int i = base + tid; i < end; i += BLK2) {
        int lr = ((unsigned)tmp1[i].x) >> 17;
        atomicAdd(&rcnt[lr], 1);
    }
    __syncthreads();
    // exclusive scan over 512 counts (waves 0-7, shfl; 3 barriers total)
    int v = (tid < CROWS) ? rcnt[tid] : 0;
    int incl = wave_incl_scan(v, lane);
    if (lane == 63 && wid < 8) wsum[wid] = incl;
    __syncthreads();
    if (tid < 8) {
        int w = wsum[tid];
        int ss = w;
#pragma unroll
        for (int off = 1; off < 8; off <<= 1) {
            int y = __shfl_up(ss, off, 64);
            if (tid >= off) ss += y;
        }
        wsum[tid] = ss - w;
    }
    __syncthreads();
    if (tid < CROWS) rstart[tid] = wsum[wid] + incl - v;
    __syncthreads();
    // emit CSR metadata
    if (tid < CROWS) {
        int gr = (b << CSHIFT) + tid;
        if (gr < n_nodes) {
            row_start[gr] = base + rstart[tid];
            row_cnt[gr]   = v;
        }
    }
    // scatter to row-sorted positions (block-private ~130 KB window, L2-hot)
    for (int i = base + tid; i < end; i += BLK2) {
        int2 p = tmp1[i];
        int lr = ((unsigned)p.x) >> 17;
        int pos = base + rstart[lr] + atomicAdd(&rcur[lr], 1);
        pcv[pos] = make_int2(p.x & 0x1FFFF, p.y);
    }
}

// ---------- accumulate: one wave per row, fp16 gathers (exact R0 body) ----------
__global__ __launch_bounds__(256) void k_rows_h(const int2* __restrict__ pcv,
                                                const int* __restrict__ row_start,
                                                const int* __restrict__ row_cnt,
                                                const __half2* __restrict__ eb,
                                                float* __restrict__ out, int n_nodes) {
    int gtid = blockIdx.x * blockDim.x + threadIdx.x;
    int r = gtid >> 6;
    int lane = threadIdx.x & 63;
    if (r >= n_nodes) return;

    int start = row_start[r];
    int end   = start + row_cnt[r];

    float2 acc = make_float2(0.f, 0.f);

    int i = start;
    for (; i + 8 <= end; i += 8) {
        int2 p[8];
#pragma unroll
        for (int k = 0; k < 8; ++k) p[k] = pcv[i + k];
        __half2 h[8];
#pragma unroll
        for (int k = 0; k < 8; ++k) h[k] = eb[(size_t)p[k].x * 64 + lane];
#pragma unroll
        for (int k = 0; k < 8; ++k) {
            float v = __int_as_float(p[k].y);
            float2 f = __half22float2(h[k]);
            acc.x += v * f.x;
            acc.y += v * f.y;
        }
    }
    for (; i < end; ++i) {
        int2 p = pcv[i];
        float v = __int_as_float(p.y);
        float2 f = __half22float2(eb[(size_t)p.x * 64 + lane]);
        acc.x += v * f.x;
        acc.y += v * f.y;
    }
    reinterpret_cast<float2*>(out)[(size_t)r * 64 + lane] = acc;
}

// ---------- fallback: atomic scatter ----------
__global__ void gcn_scatter_atomic(const int* __restrict__ edge_row,
                                   const int* __restrict__ edge_col,
                                   const float* __restrict__ edge_val,
                                   const float* __restrict__ embs,
                                   float* __restrict__ out, int n_edges) {
    long long tid = (long long)blockIdx.x * blockDim.x + threadIdx.x;
    int sub = (int)(tid & 31);
    long long edge = tid >> 5;
    if (edge >= n_edges) return;
    int r = edge_row[edge];
    int c = edge_col[edge];
    float v = edge_val[edge];
    const float4* src = reinterpret_cast<const float4*>(embs + (size_t)c * D_FEAT);
    float4 m = src[sub];
    float* dst = out + (size_t)r * D_FEAT + (size_t)sub * 4;
    atomicAdd(dst + 0, m.x * v);
    atomicAdd(dst + 1, m.y * v);
    atomicAdd(dst + 2, m.z * v);
    atomicAdd(dst + 3, m.w * v);
}

extern "C" void kernel_launch(void* const* d_in, const int* in_sizes, int n_in,
                              void* d_out, int out_size, void* d_ws, size_t ws_size,
                              hipStream_t stream) {
    const int*   edge_row = (const int*)d_in[0];
    const int*   edge_col = (const int*)d_in[1];
    const float* edge_val = (const float*)d_in[2];
    const float* embs     = (const float*)d_in[3];
    float*       out      = (float*)d_out;

    const int n_edges = in_sizes[0];
    const int n_nodes = out_size / D_FEAT;
    const int nbc = (n_nodes + CROWS - 1) >> CSHIFT;

    // Workspace layout
    char* ws = (char*)d_ws;
    const size_t off_pcv       = 0;
    const size_t off_row_start = off_pcv + (size_t)n_edges * 8;
    const size_t off_row_cnt   = off_row_start + (size_t)n_nodes * 4;
    const size_t off_cbhist    = off_row_cnt + (size_t)n_nodes * 4;
    const size_t off_gcur      = off_cbhist + (size_t)HB * MAXNBC * 4;
    const size_t off_cstart    = off_gcur + (size_t)MAXNBC * PAD * 4;
    const size_t off_embs16    = (off_cstart + (size_t)(MAXNBC + 1) * 4 + 15) & ~(size_t)15;
    const size_t full_ws       = off_embs16 + (size_t)n_nodes * D_FEAT * 2;

    // tmp1 aliases d_out (consumed by k_part2 before k_rows_h writes out).
    bool tmp_fits = ((size_t)n_edges * 8 <= (size_t)out_size * 4);
    bool packs_ok = (n_nodes <= 131072) && (nbc <= MAXNBC);  // 17-bit col, 9-bit lr

    if (ws_size < full_ws || !tmp_fits || !packs_ok) {
        hipMemsetAsync(d_out, 0, (size_t)out_size * sizeof(float), stream);
        long long total = (long long)n_edges * 32;
        int blocks = (int)((total + 255) / 256);
        gcn_scatter_atomic<<<blocks, 256, 0, stream>>>(edge_row, edge_col, edge_val,
                                                       embs, out, n_edges);
        return;
    }

    int2*   pcv       = (int2*)(ws + off_pcv);
    int*    row_start = (int*)(ws + off_row_start);
    int*    row_cnt   = (int*)(ws + off_row_cnt);
    int*    cbhist    = (int*)(ws + off_cbhist);
    int*    gcur      = (int*)(ws + off_gcur);
    int*    cstart    = (int*)(ws + off_cstart);
    __half* embs16    = (__half*)(ws + off_embs16);
    int2*   tmp1      = (int2*)d_out;

    const int nchunks = (n_edges + EPB - 1) / EPB;
    const int nf4p = n_nodes * (D_FEAT / 8);       // 2x float4 per thread
    const int conv_blocks = (nf4p + 255) / 256;

    k_hist_conv<<<HB + conv_blocks, 256, 0, stream>>>(
        edge_row, cbhist, n_edges, nbc, embs, embs16, nf4p);
    k_cscan<<<1, 256, 0, stream>>>(cbhist, cstart, gcur, nbc);
    k_part1<<<nchunks, BLK, 0, stream>>>(edge_row, edge_col, edge_val,
                                         gcur, tmp1, n_edges, nbc);
    k_part2<<<nbc, BLK2, 0, stream>>>(tmp1, cstart, pcv, row_start, row_cnt, n_nodes);

    long long rows_threads = (long long)n_nodes * 64;
    int rblocks = (int)((rows_threads + 255) / 256);
    k_rows_h<<<rblocks, 256, 0, stream>>>(pcv, row_start, row_cnt,
                                          (const __half2*)embs16, out, n_nodes);
}